// Round 9
// baseline (1291.385 us; speedup 1.0000x reference)
//
#include <hip/hip_runtime.h>

#define NB      16
#define NPTS    4096
#define NPOINT  1024
#define NSAMPLE 32

typedef float v2f  __attribute__((ext_vector_type(2)));
typedef float sv16 __attribute__((ext_vector_type(16)));

// ---- packed f32 ops (VOP3P, exact IEEE RN per half; NOT fused) ----
__device__ __forceinline__ v2f pk_add(v2f a, v2f b) {
  v2f d;
  asm("v_pk_add_f32 %0, %1, %2" : "=v"(d) : "v"(a), "v"(b));
  return d;
}
__device__ __forceinline__ v2f pk_mul(v2f a, v2f b) {
  v2f d;
  asm("v_pk_mul_f32 %0, %1, %2" : "=v"(d) : "v"(a), "v"(b));
  return d;
}
__device__ __forceinline__ float fnegx(float x) {
  return __int_as_float(__float_as_int(x) ^ 0x80000000);
}

// ---- scalar-memory weight loads (SMEM -> SGPR; feeds v_fma s-src) ----
__device__ __forceinline__ void sload16(const float* p, int boff, sv16& a) {
  asm volatile("s_load_dwordx16 %0, %1, %2\n\t"
               "s_waitcnt lgkmcnt(0)"
               : "=&s"(a)
               : "s"(p), "i"(boff));
}
__device__ __forceinline__ void sload32(const float* p, int boff, sv16& a, sv16& b) {
  asm volatile("s_load_dwordx16 %0, %2, %3\n\t"
               "s_load_dwordx16 %1, %2, %4\n\t"
               "s_waitcnt lgkmcnt(0)"
               : "=&s"(a), "=&s"(b)
               : "s"(p), "i"(boff), "i"(boff + 64));
}
#define EL32(a, b, j) ((j) < 16 ? (a)[(j) & 15] : (b)[(j) & 15])

// ---------------- DPP / swizzle u64-key max helpers ----------------
template <int C>
__device__ __forceinline__ int dppi(int v) {
  return __builtin_amdgcn_update_dpp(0, v, C, 0xf, 0xf, true);
}
template <int C>
__device__ __forceinline__ unsigned long long dppmax_u64(unsigned long long k) {
  int lo = dppi<C>((int)(unsigned)k);
  int hi = dppi<C>((int)(k >> 32));
  unsigned long long o = ((unsigned long long)(unsigned)hi << 32) | (unsigned)lo;
  return o > k ? o : k;
}
__device__ __forceinline__ unsigned long long swzmax16_u64(unsigned long long k) {
  int lo = __builtin_amdgcn_ds_swizzle((int)(unsigned)k, 0x401F);  // lane ^= 16
  int hi = __builtin_amdgcn_ds_swizzle((int)(k >> 32), 0x401F);
  unsigned long long o = ((unsigned long long)(unsigned)hi << 32) | (unsigned)lo;
  return o > k ? o : k;
}

// LDS padded to 84 KB: 163840/86016 = 1 -> a CU can NEVER host 2 blocks
// (R7's regression: P1 blocks co-resident with FPS blocks stole VALU issue).
union SharedB {
  struct {
    float4 lc4[NPTS];                // coords: winner lookup = 1 ds_read_b128
    float scen[NPOINT * 3];          // center buffer, flushed once
    unsigned long long part[2][16];  // double-buffered partials
  } f;
  float sw[4096];                    // p1 view: staged W0[3:67]
  char pad[86016];
};

// ---------------------------------------------------------------------------
// Fused FPS + P1, one block per CU. Blocks 0..15: FPS v6 core (+float4 coord
// table). Blocks 16..143: P1 (hidden under FPS's 650us shadow).
// ---------------------------------------------------------------------------
__global__ __launch_bounds__(512) void fps_p1_kernel(
    const float* __restrict__ xyz, const float* __restrict__ pts,
    const float* __restrict__ W0, float* __restrict__ out_xyz,
    float* __restrict__ P1) {
  __shared__ SharedB sm;
  const int t = threadIdx.x;
  if (blockIdx.x < NB) {
    // ================= FPS =================
    const int b = blockIdx.x;
    const int lane = t & 63;
    const float* g = xyz + (size_t)b * NPTS * 3;
    for (int j = t; j < NPTS; j += 512)
      sm.f.lc4[j] = make_float4(g[3 * j], g[3 * j + 1], g[3 * j + 2], 0.0f);
    __syncthreads();
    v2f px2[4], py2[4], pz2[4], mind2[4];
    unsigned nlo[8];
#pragma unroll
    for (int p = 0; p < 4; ++p) {
      const int j0 = t + 512 * (2 * p);
      const float4 a = sm.f.lc4[j0];
      const float4 c = sm.f.lc4[j0 + 512];
      px2[p] = (v2f){a.x, c.x};
      py2[p] = (v2f){a.y, c.y};
      pz2[p] = (v2f){a.z, c.z};
      mind2[p] = (v2f){1e10f, 1e10f};
      nlo[2 * p] = ~(unsigned)j0;
      nlo[2 * p + 1] = ~(unsigned)(j0 + 512);
    }
    float cx, cy, cz;
    {
      const float4 c0 = sm.f.lc4[0];
      cx = c0.x; cy = c0.y; cz = c0.z;
    }
    for (int it = 0; it < NPOINT; ++it) {
      if (t == 0) {
        sm.f.scen[3 * it] = cx; sm.f.scen[3 * it + 1] = cy; sm.f.scen[3 * it + 2] = cz;
      }
      const float ncx = fnegx(cx), ncy = fnegx(cy), ncz = fnegx(cz);
      const v2f ncxx = (v2f){ncx, ncx};
      const v2f ncyy = (v2f){ncy, ncy};
      const v2f nczz = (v2f){ncz, ncz};
#pragma unroll
      for (int p = 0; p < 4; ++p) {
        const v2f dx = pk_add(px2[p], ncxx);
        const v2f dy = pk_add(py2[p], ncyy);
        const v2f dz = pk_add(pz2[p], nczz);
        const v2f xx = pk_mul(dx, dx);
        const v2f yy = pk_mul(dy, dy);
        const v2f zz = pk_mul(dz, dz);
        v2f s = pk_add(xx, yy);
        s = pk_add(s, zz);
        mind2[p].x = fminf(mind2[p].x, s.x);
        mind2[p].y = fminf(mind2[p].y, s.y);
      }
      unsigned long long k[8];
#pragma unroll
      for (int p = 0; p < 4; ++p) {
        k[2 * p] = ((unsigned long long)__float_as_uint(mind2[p].x) << 32) | nlo[2 * p];
        k[2 * p + 1] =
            ((unsigned long long)__float_as_uint(mind2[p].y) << 32) | nlo[2 * p + 1];
      }
#pragma unroll
      for (int s = 4; s; s >>= 1)
#pragma unroll
        for (int i = 0; i < s; ++i) k[i] = k[i] > k[i + s] ? k[i] : k[i + s];
      unsigned long long key = k[0];
      key = dppmax_u64<0xB1>(key);   // xor 1
      key = dppmax_u64<0x4E>(key);   // xor 2
      key = dppmax_u64<0x141>(key);  // half-mirror (covers 8)
      key = dppmax_u64<0x140>(key);  // mirror (covers 16)
      key = swzmax16_u64(key);       // xor 16 -> 32-lane uniform
      const int buf = it & 1;
      if ((lane & 31) == 0) sm.f.part[buf][(t >> 6) * 2 + (lane >> 5)] = key;
      __syncthreads();
      unsigned long long rk = sm.f.part[buf][lane & 15];
      rk = dppmax_u64<0xB1>(rk);
      rk = dppmax_u64<0x4E>(rk);
      rk = dppmax_u64<0x141>(rk);
      rk = dppmax_u64<0x140>(rk);
      const unsigned idx = ~(unsigned)rk;  // winner (block-uniform)
      const float4 c4 = sm.f.lc4[idx];     // ONE broadcast ds_read_b128
      cx = c4.x; cy = c4.y; cz = c4.z;
    }
    __syncthreads();
    float* ob = out_xyz + (size_t)b * NPOINT * 3;
    for (int i = t; i < NPOINT * 3; i += 512) ob[i] = sm.f.scen[i];
  } else {
    // ================= P1 (one row per thread) =================
    {
      const float4* w4 = (const float4*)(W0 + 192);
      float4* s4 = (float4*)sm.sw;
      s4[t] = w4[t]; s4[t + 512] = w4[t + 512];
    }
    __syncthreads();
    const size_t r = (size_t)(blockIdx.x - NB) * 512 + t;
    const float* prow = pts + r * 64;
    float acc[64];
#pragma unroll
    for (int d = 0; d < 64; ++d) acc[d] = 0.0f;
#pragma unroll
    for (int cq = 0; cq < 16; ++cq) {
      const float4 p4 = *(const float4*)(prow + cq * 4);
      const float pv[4] = {p4.x, p4.y, p4.z, p4.w};
#pragma unroll
      for (int u = 0; u < 4; ++u) {
        const int c = cq * 4 + u;
#pragma unroll
        for (int d4 = 0; d4 < 16; ++d4) {
          const float4 w = *(const float4*)(&sm.sw[c * 64 + d4 * 4]);
          acc[d4 * 4 + 0] = fmaf(pv[u], w.x, acc[d4 * 4 + 0]);
          acc[d4 * 4 + 1] = fmaf(pv[u], w.y, acc[d4 * 4 + 1]);
          acc[d4 * 4 + 2] = fmaf(pv[u], w.z, acc[d4 * 4 + 2]);
          acc[d4 * 4 + 3] = fmaf(pv[u], w.w, acc[d4 * 4 + 3]);
        }
      }
    }
    float* o = P1 + r * 64;
#pragma unroll
    for (int d4 = 0; d4 < 16; ++d4)
      *(float4*)(o + d4 * 4) = make_float4(acc[d4 * 4 + 0], acc[d4 * 4 + 1],
                                           acc[d4 * 4 + 2], acc[d4 * 4 + 3]);
  }
}

// ---------------------------------------------------------------------------
// Ball query (proven R6): one wave per query; ballot + prefix popcount;
// uniform early exit at 32 hits.
// ---------------------------------------------------------------------------
__global__ __launch_bounds__(256) void ballq_kernel(const float* __restrict__ xyz,
                                                    const float* __restrict__ new_xyz,
                                                    int* __restrict__ ballidx,
                                                    float* __restrict__ out_idx) {
  __shared__ int sidx[4][NSAMPLE];
  const int wv = threadIdx.x >> 6, lane = threadIdx.x & 63;
  const int q = blockIdx.x * 4 + wv;
  const int b = q >> 10;
  const float* g = xyz + (size_t)b * NPTS * 3;
  const float nx = new_xyz[(size_t)q * 3];
  const float ny = new_xyz[(size_t)q * 3 + 1];
  const float nz = new_xyz[(size_t)q * 3 + 2];
  const float r2 = (float)(0.2 * 0.2);  // double->f32 (NOT 0.2f*0.2f)
  int cnt = 0;
  for (int base = 0; base < NPTS; base += 64) {
    const int j = base + lane;
    const float dx = __fsub_rn(g[3 * j], nx);
    const float dy = __fsub_rn(g[3 * j + 1], ny);
    const float dz = __fsub_rn(g[3 * j + 2], nz);
    const float d2 = __fadd_rn(__fadd_rn(__fmul_rn(dx, dx), __fmul_rn(dy, dy)),
                               __fmul_rn(dz, dz));
    const bool hit = d2 <= r2;
    const unsigned long long m = __ballot(hit);
    const int pos = cnt + __popcll(m & ((1ull << lane) - 1ull));
    if (hit && pos < NSAMPLE) sidx[wv][pos] = j;
    cnt += __popcll(m);
    if (cnt >= NSAMPLE) break;  // wave-uniform
  }
  __syncthreads();
  const int capped = cnt < NSAMPLE ? cnt : NSAMPLE;
  if (lane < NSAMPLE) {
    const int v = sidx[wv][lane < capped ? lane : 0];  // pad with first hit
    ballidx[(size_t)q * NSAMPLE + lane] = v;
    out_idx[(size_t)q * NSAMPLE + lane] = (float)v;
  }
}

// ---------------------------------------------------------------------------
// MLP v2: weights via s_load -> SGPRs (scalar cache), fma reads SGPR src0.
// Removes the 3072 uniform VMEM loads/thread that thrashed L1. Layers 2/3
// are a pure VALU stream; expression order identical to R6 -> same bits.
// ---------------------------------------------------------------------------
__global__ __launch_bounds__(256) void mlp_kernel(
    const float* __restrict__ xyz, const float* __restrict__ new_xyz,
    const int* __restrict__ ballidx, const float* __restrict__ P1,
    const float* __restrict__ W0, const float* __restrict__ b0,
    const float* __restrict__ W1, const float* __restrict__ b1,
    const float* __restrict__ W2, const float* __restrict__ b2,
    float* __restrict__ out_np) {
  const int t = threadIdx.x;
  const int item = blockIdx.x * 256 + t;
  const int k = item & 31;
  const int q = item >> 5;
  const int b = q >> 10;
  const int idx = ballidx[(size_t)q * 32 + k];
  const float nx = new_xyz[(size_t)q * 3];
  const float ny = new_xyz[(size_t)q * 3 + 1];
  const float nz = new_xyz[(size_t)q * 3 + 2];
  const float* p = xyz + ((size_t)b * NPTS + idx) * 3;
  const float dx = p[0] - nx, dy = p[1] - ny, dz = p[2] - nz;

  // ---- layer 1: h1 = relu(P1[idx] + dx*W0r0 + dy*W0r1 + dz*W0r2 + b0) ----
  float h1[64];
  const float* p1r = P1 + ((size_t)b * NPTS + idx) * 64;
#pragma unroll
  for (int dq = 0; dq < 4; ++dq) {
    sv16 wx, wy, wz, bv;
    sload16(W0, dq * 64, wx);
    sload16(W0, 256 + dq * 64, wy);
    sload16(W0, 512 + dq * 64, wz);
    sload16(b0, dq * 64, bv);
#pragma unroll
    for (int u4 = 0; u4 < 4; ++u4) {
      const float4 pv = *(const float4*)(p1r + dq * 16 + u4 * 4);
      const float pe[4] = {pv.x, pv.y, pv.z, pv.w};
#pragma unroll
      for (int u = 0; u < 4; ++u) {
        const int e = u4 * 4 + u;
        const float v = pe[u] + dx * wx[e] + dy * wy[e] + dz * wz[e] + bv[e];
        h1[dq * 16 + e] = fmaxf(v, 0.0f);
      }
    }
  }

  // ---- layer 2 ----
  float h2[64];
  {
    sv16 ba, bb;
    sload32(b1, 0, ba, bb);
#pragma unroll
    for (int j = 0; j < 32; ++j) h2[j] = EL32(ba, bb, j);
    sv16 bc, bd;
    sload32(b1, 128, bc, bd);
#pragma unroll
    for (int j = 0; j < 32; ++j) h2[32 + j] = EL32(bc, bd, j);
  }
#pragma unroll
  for (int c = 0; c < 64; ++c) {
    const float hc = h1[c];
    sv16 wa, wb;
    sload32(W1, c * 256, wa, wb);
#pragma unroll
    for (int j = 0; j < 32; ++j) h2[j] = fmaf(hc, EL32(wa, wb, j), h2[j]);
    sv16 wc, wd;
    sload32(W1, c * 256 + 128, wc, wd);
#pragma unroll
    for (int j = 0; j < 32; ++j) h2[32 + j] = fmaf(hc, EL32(wc, wd, j), h2[32 + j]);
  }
#pragma unroll
  for (int j = 0; j < 64; ++j) h2[j] = fmaxf(h2[j], 0.0f);

  // ---- layer 3 in two 64-col halves + k-max reduce + store ----
  float* outq = out_np + (size_t)q * 128;
#pragma unroll
  for (int jh = 0; jh < 2; ++jh) {
    float acc[64];
    {
      sv16 ba, bb;
      sload32(b2, jh * 256, ba, bb);
#pragma unroll
      for (int j = 0; j < 32; ++j) acc[j] = EL32(ba, bb, j);
      sv16 bc, bd;
      sload32(b2, jh * 256 + 128, bc, bd);
#pragma unroll
      for (int j = 0; j < 32; ++j) acc[32 + j] = EL32(bc, bd, j);
    }
#pragma unroll
    for (int c = 0; c < 64; ++c) {
      const float hc = h2[c];
      sv16 wa, wb;
      sload32(W2, c * 512 + jh * 256, wa, wb);
#pragma unroll
      for (int j = 0; j < 32; ++j) acc[j] = fmaf(hc, EL32(wa, wb, j), acc[j]);
      sv16 wc, wd;
      sload32(W2, c * 512 + jh * 256 + 128, wc, wd);
#pragma unroll
      for (int j = 0; j < 32; ++j) acc[32 + j] = fmaf(hc, EL32(wc, wd, j), acc[32 + j]);
    }
#pragma unroll
    for (int j = 0; j < 64; ++j) acc[j] = fmaxf(acc[j], 0.0f);
#pragma unroll
    for (int msk = 16; msk >= 1; msk >>= 1) {
#pragma unroll
      for (int j = 0; j < 64; ++j) acc[j] = fmaxf(acc[j], __shfl_xor(acc[j], msk, 64));
    }
    if (k == 0) {
#pragma unroll
      for (int j8 = 0; j8 < 16; ++j8)
        *(float4*)(outq + jh * 64 + j8 * 4) =
            make_float4(acc[j8 * 4 + 0], acc[j8 * 4 + 1], acc[j8 * 4 + 2], acc[j8 * 4 + 3]);
    }
  }
}

extern "C" void kernel_launch(void* const* d_in, const int* in_sizes, int n_in,
                              void* d_out, int out_size, void* d_ws, size_t ws_size,
                              hipStream_t stream) {
  const float* xyz = (const float*)d_in[0];
  const float* pts = (const float*)d_in[1];
  const float* W0  = (const float*)d_in[2];
  const float* b0  = (const float*)d_in[3];
  const float* W1  = (const float*)d_in[4];
  const float* b1  = (const float*)d_in[5];
  const float* W2  = (const float*)d_in[6];
  const float* b2  = (const float*)d_in[7];

  float* out      = (float*)d_out;
  float* out_xyz  = out;                       // [16,1024,3]
  float* out_np   = out + 16 * 1024 * 3;       // [16,1024,128]
  float* out_idx  = out_np + 16 * 1024 * 128;  // [16,1024,32] as float values

  int*   ballidx = (int*)d_ws;                          // 2 MB
  float* P1      = (float*)((char*)d_ws + (2u << 20));  // 16 MB

  fps_p1_kernel<<<NB + 128, 512, 0, stream>>>(xyz, pts, W0, out_xyz, P1);
  ballq_kernel<<<4096, 256, 0, stream>>>(xyz, out_xyz, ballidx, out_idx);
  mlp_kernel<<<2048, 256, 0, stream>>>(xyz, out_xyz, ballidx, P1,
                                       W0, b0, W1, b1, W2, b2, out_np);
}

// Round 11
// 1204.123 us; speedup vs baseline: 1.0725x; 1.0725x over previous
//
#include <hip/hip_runtime.h>

#define NB      16
#define NPTS    4096
#define NPOINT  1024
#define NSAMPLE 32

typedef float v2f __attribute__((ext_vector_type(2)));

// ---- packed f32 ops (VOP3P; per-half IEEE RN). NOTE: v_pk_max_f32 does NOT
//      exist on gfx950 (R10 compile fail) -- max stays scalar fmaxf. ----
__device__ __forceinline__ v2f pk_add(v2f a, v2f b) {
  v2f d;
  asm("v_pk_add_f32 %0, %1, %2" : "=v"(d) : "v"(a), "v"(b));
  return d;
}
__device__ __forceinline__ v2f pk_mul(v2f a, v2f b) {
  v2f d;
  asm("v_pk_mul_f32 %0, %1, %2" : "=v"(d) : "v"(a), "v"(b));
  return d;
}
__device__ __forceinline__ v2f pk_fma(v2f a, v2f b, v2f c) {  // == fmaf per half
  v2f d;
  asm("v_pk_fma_f32 %0, %1, %2, %3" : "=v"(d) : "v"(a), "v"(b), "v"(c));
  return d;
}
__device__ __forceinline__ float fnegx(float x) {
  return __int_as_float(__float_as_int(x) ^ 0x80000000);
}

// ---------------- DPP / swizzle u64-key max helpers ----------------
template <int C>
__device__ __forceinline__ int dppi(int v) {
  return __builtin_amdgcn_update_dpp(0, v, C, 0xf, 0xf, true);
}
template <int C>
__device__ __forceinline__ unsigned long long dppmax_u64(unsigned long long k) {
  int lo = dppi<C>((int)(unsigned)k);
  int hi = dppi<C>((int)(k >> 32));
  unsigned long long o = ((unsigned long long)(unsigned)hi << 32) | (unsigned)lo;
  return o > k ? o : k;
}
__device__ __forceinline__ unsigned long long swzmax16_u64(unsigned long long k) {
  int lo = __builtin_amdgcn_ds_swizzle((int)(unsigned)k, 0x401F);  // lane ^= 16
  int hi = __builtin_amdgcn_ds_swizzle((int)(k >> 32), 0x401F);
  unsigned long long o = ((unsigned long long)(unsigned)hi << 32) | (unsigned)lo;
  return o > k ? o : k;
}

// FPS view = exact v6 layout (lx/ly/lz). Pad keeps 1 block/CU.
union SharedB {
  struct {
    float lx[NPTS], ly[NPTS], lz[NPTS];
    float scen[NPOINT * 3];
    unsigned long long part[2][16];
  } f;
  float sw[4096];  // p1 view: staged W0[3:67]
  char pad[86016];
};

// ---------------------------------------------------------------------------
// Fused FPS + P1. Blocks 0..15: FPS v6 core verbatim (proven 647us alone).
// Blocks 16..143: P1 (hidden under FPS's shadow; proven in R7/R9).
// ---------------------------------------------------------------------------
__global__ __launch_bounds__(512) void fps_p1_kernel(
    const float* __restrict__ xyz, const float* __restrict__ pts,
    const float* __restrict__ W0, float* __restrict__ out_xyz,
    float* __restrict__ P1) {
  __shared__ SharedB sm;
  const int t = threadIdx.x;
  if (blockIdx.x < NB) {
    // ================= FPS (v6 core) =================
    const int b = blockIdx.x;
    const int lane = t & 63;
    const float* g = xyz + (size_t)b * NPTS * 3;
    for (int j = t; j < NPTS; j += 512) {
      sm.f.lx[j] = g[3 * j]; sm.f.ly[j] = g[3 * j + 1]; sm.f.lz[j] = g[3 * j + 2];
    }
    __syncthreads();
    v2f px2[4], py2[4], pz2[4], mind2[4];
    unsigned nlo[8];
#pragma unroll
    for (int p = 0; p < 4; ++p) {
      const int j0 = t + 512 * (2 * p);
      px2[p] = (v2f){sm.f.lx[j0], sm.f.lx[j0 + 512]};
      py2[p] = (v2f){sm.f.ly[j0], sm.f.ly[j0 + 512]};
      pz2[p] = (v2f){sm.f.lz[j0], sm.f.lz[j0 + 512]};
      mind2[p] = (v2f){1e10f, 1e10f};
      nlo[2 * p] = ~(unsigned)j0;
      nlo[2 * p + 1] = ~(unsigned)(j0 + 512);
    }
    float cx = sm.f.lx[0], cy = sm.f.ly[0], cz = sm.f.lz[0];
    for (int it = 0; it < NPOINT; ++it) {
      if (t == 0) {
        sm.f.scen[3 * it] = cx; sm.f.scen[3 * it + 1] = cy; sm.f.scen[3 * it + 2] = cz;
      }
      const float ncx = fnegx(cx), ncy = fnegx(cy), ncz = fnegx(cz);
      const v2f ncxx = (v2f){ncx, ncx};
      const v2f ncyy = (v2f){ncy, ncy};
      const v2f nczz = (v2f){ncz, ncz};
#pragma unroll
      for (int p = 0; p < 4; ++p) {
        const v2f dx = pk_add(px2[p], ncxx);
        const v2f dy = pk_add(py2[p], ncyy);
        const v2f dz = pk_add(pz2[p], nczz);
        const v2f xx = pk_mul(dx, dx);
        const v2f yy = pk_mul(dy, dy);
        const v2f zz = pk_mul(dz, dz);
        v2f s = pk_add(xx, yy);
        s = pk_add(s, zz);
        mind2[p].x = fminf(mind2[p].x, s.x);
        mind2[p].y = fminf(mind2[p].y, s.y);
      }
      unsigned long long k[8];
#pragma unroll
      for (int p = 0; p < 4; ++p) {
        k[2 * p] = ((unsigned long long)__float_as_uint(mind2[p].x) << 32) | nlo[2 * p];
        k[2 * p + 1] =
            ((unsigned long long)__float_as_uint(mind2[p].y) << 32) | nlo[2 * p + 1];
      }
#pragma unroll
      for (int s = 4; s; s >>= 1)
#pragma unroll
        for (int i = 0; i < s; ++i) k[i] = k[i] > k[i + s] ? k[i] : k[i + s];
      unsigned long long key = k[0];
      key = dppmax_u64<0xB1>(key);   // xor 1
      key = dppmax_u64<0x4E>(key);   // xor 2
      key = dppmax_u64<0x141>(key);  // half-mirror (covers 8)
      key = dppmax_u64<0x140>(key);  // mirror (covers 16)
      key = swzmax16_u64(key);       // xor 16 -> 32-lane uniform
      const int buf = it & 1;
      if ((lane & 31) == 0) sm.f.part[buf][(t >> 6) * 2 + (lane >> 5)] = key;
      __syncthreads();
      unsigned long long rk = sm.f.part[buf][lane & 15];
      rk = dppmax_u64<0xB1>(rk);
      rk = dppmax_u64<0x4E>(rk);
      rk = dppmax_u64<0x141>(rk);
      rk = dppmax_u64<0x140>(rk);
      const unsigned idx = ~(unsigned)rk;  // winner (block-uniform)
      cx = sm.f.lx[idx]; cy = sm.f.ly[idx]; cz = sm.f.lz[idx];  // 3 broadcast reads
    }
    __syncthreads();
    float* ob = out_xyz + (size_t)b * NPOINT * 3;
    for (int i = t; i < NPOINT * 3; i += 512) ob[i] = sm.f.scen[i];
  } else {
    // ================= P1 (one row per thread) =================
    {
      const float4* w4 = (const float4*)(W0 + 192);
      float4* s4 = (float4*)sm.sw;
      s4[t] = w4[t]; s4[t + 512] = w4[t + 512];
    }
    __syncthreads();
    const size_t r = (size_t)(blockIdx.x - NB) * 512 + t;
    const float* prow = pts + r * 64;
    float acc[64];
#pragma unroll
    for (int d = 0; d < 64; ++d) acc[d] = 0.0f;
#pragma unroll
    for (int cq = 0; cq < 16; ++cq) {
      const float4 p4 = *(const float4*)(prow + cq * 4);
      const float pv[4] = {p4.x, p4.y, p4.z, p4.w};
#pragma unroll
      for (int u = 0; u < 4; ++u) {
        const int c = cq * 4 + u;
#pragma unroll
        for (int d4 = 0; d4 < 16; ++d4) {
          const float4 w = *(const float4*)(&sm.sw[c * 64 + d4 * 4]);
          acc[d4 * 4 + 0] = fmaf(pv[u], w.x, acc[d4 * 4 + 0]);
          acc[d4 * 4 + 1] = fmaf(pv[u], w.y, acc[d4 * 4 + 1]);
          acc[d4 * 4 + 2] = fmaf(pv[u], w.z, acc[d4 * 4 + 2]);
          acc[d4 * 4 + 3] = fmaf(pv[u], w.w, acc[d4 * 4 + 3]);
        }
      }
    }
    float* o = P1 + r * 64;
#pragma unroll
    for (int d4 = 0; d4 < 16; ++d4)
      *(float4*)(o + d4 * 4) = make_float4(acc[d4 * 4 + 0], acc[d4 * 4 + 1],
                                           acc[d4 * 4 + 2], acc[d4 * 4 + 3]);
  }
}

// ---------------------------------------------------------------------------
// Ball query (proven R6): one wave per query; ballot + prefix popcount;
// uniform early exit at 32 hits.
// ---------------------------------------------------------------------------
__global__ __launch_bounds__(256) void ballq_kernel(const float* __restrict__ xyz,
                                                    const float* __restrict__ new_xyz,
                                                    int* __restrict__ ballidx,
                                                    float* __restrict__ out_idx) {
  __shared__ int sidx[4][NSAMPLE];
  const int wv = threadIdx.x >> 6, lane = threadIdx.x & 63;
  const int q = blockIdx.x * 4 + wv;
  const int b = q >> 10;
  const float* g = xyz + (size_t)b * NPTS * 3;
  const float nx = new_xyz[(size_t)q * 3];
  const float ny = new_xyz[(size_t)q * 3 + 1];
  const float nz = new_xyz[(size_t)q * 3 + 2];
  const float r2 = (float)(0.2 * 0.2);  // double->f32 (NOT 0.2f*0.2f)
  int cnt = 0;
  for (int base = 0; base < NPTS; base += 64) {
    const int j = base + lane;
    const float dx = __fsub_rn(g[3 * j], nx);
    const float dy = __fsub_rn(g[3 * j + 1], ny);
    const float dz = __fsub_rn(g[3 * j + 2], nz);
    const float d2 = __fadd_rn(__fadd_rn(__fmul_rn(dx, dx), __fmul_rn(dy, dy)),
                               __fmul_rn(dz, dz));
    const bool hit = d2 <= r2;
    const unsigned long long m = __ballot(hit);
    const int pos = cnt + __popcll(m & ((1ull << lane) - 1ull));
    if (hit && pos < NSAMPLE) sidx[wv][pos] = j;
    cnt += __popcll(m);
    if (cnt >= NSAMPLE) break;  // wave-uniform
  }
  __syncthreads();
  const int capped = cnt < NSAMPLE ? cnt : NSAMPLE;
  if (lane < NSAMPLE) {
    const int v = sidx[wv][lane < capped ? lane : 0];  // pad with first hit
    ballidx[(size_t)q * NSAMPLE + lane] = v;
    out_idx[(size_t)q * NSAMPLE + lane] = (float)v;
  }
}

// ---------------------------------------------------------------------------
// MLP v3 = R6 structure (VMEM uniform weight loads, L2-hot) with layers 2/3
// accumulating via v_pk_fma_f32 (2 fma/instr). relu/maxpool stay scalar
// fmaxf (no v_pk_max_f32 on gfx950). Bit-identical to R6's output.
// ---------------------------------------------------------------------------
__global__ __launch_bounds__(256) void mlp_kernel(
    const float* __restrict__ xyz, const float* __restrict__ new_xyz,
    const int* __restrict__ ballidx, const float* __restrict__ P1,
    const float* __restrict__ W0, const float* __restrict__ b0,
    const float* __restrict__ W1, const float* __restrict__ b1,
    const float* __restrict__ W2, const float* __restrict__ b2,
    float* __restrict__ out_np) {
  const int t = threadIdx.x;
  const int item = blockIdx.x * 256 + t;
  const int k = item & 31;
  const int q = item >> 5;
  const int b = q >> 10;
  const int idx = ballidx[(size_t)q * 32 + k];
  const float nx = new_xyz[(size_t)q * 3];
  const float ny = new_xyz[(size_t)q * 3 + 1];
  const float nz = new_xyz[(size_t)q * 3 + 2];
  const float* p = xyz + ((size_t)b * NPTS + idx) * 3;
  const float dx = p[0] - nx, dy = p[1] - ny, dz = p[2] - nz;

  // ---- layer 1 (scalar; small) ----
  float h1[64];
  const float* p1r = P1 + ((size_t)b * NPTS + idx) * 64;
#pragma unroll
  for (int d4 = 0; d4 < 16; ++d4) {
    const float4 pv = *(const float4*)(p1r + d4 * 4);
    const float pe[4] = {pv.x, pv.y, pv.z, pv.w};
#pragma unroll
    for (int u = 0; u < 4; ++u) {
      const int d = d4 * 4 + u;
      const float v = pe[u] + dx * W0[d] + dy * W0[64 + d] + dz * W0[128 + d] + b0[d];
      h1[d] = fmaxf(v, 0.0f);
    }
  }

  // ---- layer 2: 32 v2f accumulators, pk_fma; relu scalar ----
  v2f h2p[32];
#pragma unroll
  for (int j4 = 0; j4 < 16; ++j4) {
    const float4 bb = *(const float4*)(&b1[j4 * 4]);
    h2p[2 * j4] = (v2f){bb.x, bb.y};
    h2p[2 * j4 + 1] = (v2f){bb.z, bb.w};
  }
#pragma unroll
  for (int c = 0; c < 64; ++c) {
    const v2f hc2 = (v2f){h1[c], h1[c]};
#pragma unroll
    for (int j4 = 0; j4 < 16; ++j4) {
      const float4 w = *(const float4*)(&W1[c * 64 + j4 * 4]);
      h2p[2 * j4] = pk_fma(hc2, (v2f){w.x, w.y}, h2p[2 * j4]);
      h2p[2 * j4 + 1] = pk_fma(hc2, (v2f){w.z, w.w}, h2p[2 * j4 + 1]);
    }
  }
#pragma unroll
  for (int j = 0; j < 32; ++j) {
    h2p[j].x = fmaxf(h2p[j].x, 0.0f);
    h2p[j].y = fmaxf(h2p[j].y, 0.0f);
  }

  // ---- layer 3 in 4 chunks of 32 cols (16 v2f acc), pk_fma + k-max ----
  float* outq = out_np + (size_t)q * 128;
  for (int jb = 0; jb < 4; ++jb) {
    v2f accp[16];
#pragma unroll
    for (int j8 = 0; j8 < 8; ++j8) {
      const float4 bb = *(const float4*)(&b2[jb * 32 + j8 * 4]);
      accp[2 * j8] = (v2f){bb.x, bb.y};
      accp[2 * j8 + 1] = (v2f){bb.z, bb.w};
    }
#pragma unroll
    for (int c = 0; c < 64; ++c) {
      const float hcs = (c & 1) ? h2p[c >> 1].y : h2p[c >> 1].x;
      const v2f hc2 = (v2f){hcs, hcs};
#pragma unroll
      for (int j8 = 0; j8 < 8; ++j8) {
        const float4 w = *(const float4*)(&W2[c * 128 + jb * 32 + j8 * 4]);
        accp[2 * j8] = pk_fma(hc2, (v2f){w.x, w.y}, accp[2 * j8]);
        accp[2 * j8 + 1] = pk_fma(hc2, (v2f){w.z, w.w}, accp[2 * j8 + 1]);
      }
    }
    float acc[32];
#pragma unroll
    for (int j = 0; j < 16; ++j) {
      acc[2 * j] = fmaxf(accp[j].x, 0.0f);
      acc[2 * j + 1] = fmaxf(accp[j].y, 0.0f);
    }
#pragma unroll
    for (int msk = 16; msk >= 1; msk >>= 1) {
#pragma unroll
      for (int j = 0; j < 32; ++j) acc[j] = fmaxf(acc[j], __shfl_xor(acc[j], msk, 64));
    }
    if (k == 0) {
      // accp order: pairs (2j,2j+1) interleave as acc[2j],acc[2j+1] -> natural
#pragma unroll
      for (int j8 = 0; j8 < 8; ++j8) {
        // acc layout: acc[2*(2*j8)] = col j8*4+0 ... need col order restore:
        // accp[2*j8] held cols (4*j8, 4*j8+1); accp[2*j8+1] held (4*j8+2, 4*j8+3)
        // acc[2*(2*j8)+0]=col0, acc[2*(2*j8)+1]=col1, acc[2*(2*j8+1)+0]=col2, +1=col3
        *(float4*)(outq + jb * 32 + j8 * 4) =
            make_float4(acc[4 * j8 + 0], acc[4 * j8 + 1],
                        acc[4 * j8 + 2], acc[4 * j8 + 3]);
      }
    }
  }
}

extern "C" void kernel_launch(void* const* d_in, const int* in_sizes, int n_in,
                              void* d_out, int out_size, void* d_ws, size_t ws_size,
                              hipStream_t stream) {
  const float* xyz = (const float*)d_in[0];
  const float* pts = (const float*)d_in[1];
  const float* W0  = (const float*)d_in[2];
  const float* b0  = (const float*)d_in[3];
  const float* W1  = (const float*)d_in[4];
  const float* b1  = (const float*)d_in[5];
  const float* W2  = (const float*)d_in[6];
  const float* b2  = (const float*)d_in[7];

  float* out      = (float*)d_out;
  float* out_xyz  = out;                       // [16,1024,3]
  float* out_np   = out + 16 * 1024 * 3;       // [16,1024,128]
  float* out_idx  = out_np + 16 * 1024 * 128;  // [16,1024,32] as float values

  int*   ballidx = (int*)d_ws;                          // 2 MB
  float* P1      = (float*)((char*)d_ws + (2u << 20));  // 16 MB

  fps_p1_kernel<<<NB + 128, 512, 0, stream>>>(xyz, pts, W0, out_xyz, P1);
  ballq_kernel<<<4096, 256, 0, stream>>>(xyz, out_xyz, ballidx, out_idx);
  mlp_kernel<<<2048, 256, 0, stream>>>(xyz, out_xyz, ballidx, P1,
                                       W0, b0, W1, b1, W2, b2, out_np);
}

// Round 12
// 958.973 us; speedup vs baseline: 1.3466x; 1.2556x over previous
//
#include <hip/hip_runtime.h>

#define NB      16
#define NPTS    4096
#define NPOINT  1024
#define NSAMPLE 32

typedef float v2f __attribute__((ext_vector_type(2)));

// ---- packed f32 ops (VOP3P; per-half IEEE RN). NOTE: v_pk_max_f32 does NOT
//      exist on gfx950 (R10 compile fail). pk_fma in MLP regressed (R11,
//      likely pair-marshaling spills) -- MLP stays scalar fmaf. ----
__device__ __forceinline__ v2f pk_add(v2f a, v2f b) {
  v2f d;
  asm("v_pk_add_f32 %0, %1, %2" : "=v"(d) : "v"(a), "v"(b));
  return d;
}
__device__ __forceinline__ v2f pk_mul(v2f a, v2f b) {
  v2f d;
  asm("v_pk_mul_f32 %0, %1, %2" : "=v"(d) : "v"(a), "v"(b));
  return d;
}
__device__ __forceinline__ float fnegx(float x) {
  return __int_as_float(__float_as_int(x) ^ 0x80000000);
}

// ---------------- DPP / swizzle u64-key max helpers ----------------
template <int C>
__device__ __forceinline__ int dppi(int v) {
  return __builtin_amdgcn_update_dpp(0, v, C, 0xf, 0xf, true);
}
template <int C>
__device__ __forceinline__ unsigned long long dppmax_u64(unsigned long long k) {
  int lo = dppi<C>((int)(unsigned)k);
  int hi = dppi<C>((int)(k >> 32));
  unsigned long long o = ((unsigned long long)(unsigned)hi << 32) | (unsigned)lo;
  return o > k ? o : k;
}
__device__ __forceinline__ unsigned long long swzmax16_u64(unsigned long long k) {
  int lo = __builtin_amdgcn_ds_swizzle((int)(unsigned)k, 0x401F);  // lane ^= 16
  int hi = __builtin_amdgcn_ds_swizzle((int)(k >> 32), 0x401F);
  unsigned long long o = ((unsigned long long)(unsigned)hi << 32) | (unsigned)lo;
  return o > k ? o : k;
}

// FPS view = exact v6 layout (lx/ly/lz). Pad keeps 1 block/CU.
union SharedB {
  struct {
    float lx[NPTS], ly[NPTS], lz[NPTS];
    float scen[NPOINT * 3];
    unsigned long long part[2][16];
  } f;
  float sw[4096];  // p1 view: staged W0[3:67]
  char pad[86016];
};

// ---------------------------------------------------------------------------
// Fused FPS + P1. Blocks 0..15: FPS v6 core verbatim. Blocks 16..143: P1
// (hidden under FPS's ~680us shadow; measured stable across R9/R11).
// ---------------------------------------------------------------------------
__global__ __launch_bounds__(512) void fps_p1_kernel(
    const float* __restrict__ xyz, const float* __restrict__ pts,
    const float* __restrict__ W0, float* __restrict__ out_xyz,
    float* __restrict__ P1) {
  __shared__ SharedB sm;
  const int t = threadIdx.x;
  if (blockIdx.x < NB) {
    // ================= FPS (v6 core) =================
    const int b = blockIdx.x;
    const int lane = t & 63;
    const float* g = xyz + (size_t)b * NPTS * 3;
    for (int j = t; j < NPTS; j += 512) {
      sm.f.lx[j] = g[3 * j]; sm.f.ly[j] = g[3 * j + 1]; sm.f.lz[j] = g[3 * j + 2];
    }
    __syncthreads();
    v2f px2[4], py2[4], pz2[4], mind2[4];
    unsigned nlo[8];
#pragma unroll
    for (int p = 0; p < 4; ++p) {
      const int j0 = t + 512 * (2 * p);
      px2[p] = (v2f){sm.f.lx[j0], sm.f.lx[j0 + 512]};
      py2[p] = (v2f){sm.f.ly[j0], sm.f.ly[j0 + 512]};
      pz2[p] = (v2f){sm.f.lz[j0], sm.f.lz[j0 + 512]};
      mind2[p] = (v2f){1e10f, 1e10f};
      nlo[2 * p] = ~(unsigned)j0;
      nlo[2 * p + 1] = ~(unsigned)(j0 + 512);
    }
    float cx = sm.f.lx[0], cy = sm.f.ly[0], cz = sm.f.lz[0];
    for (int it = 0; it < NPOINT; ++it) {
      if (t == 0) {
        sm.f.scen[3 * it] = cx; sm.f.scen[3 * it + 1] = cy; sm.f.scen[3 * it + 2] = cz;
      }
      const float ncx = fnegx(cx), ncy = fnegx(cy), ncz = fnegx(cz);
      const v2f ncxx = (v2f){ncx, ncx};
      const v2f ncyy = (v2f){ncy, ncy};
      const v2f nczz = (v2f){ncz, ncz};
#pragma unroll
      for (int p = 0; p < 4; ++p) {
        const v2f dx = pk_add(px2[p], ncxx);
        const v2f dy = pk_add(py2[p], ncyy);
        const v2f dz = pk_add(pz2[p], nczz);
        const v2f xx = pk_mul(dx, dx);
        const v2f yy = pk_mul(dy, dy);
        const v2f zz = pk_mul(dz, dz);
        v2f s = pk_add(xx, yy);
        s = pk_add(s, zz);
        mind2[p].x = fminf(mind2[p].x, s.x);
        mind2[p].y = fminf(mind2[p].y, s.y);
      }
      unsigned long long k[8];
#pragma unroll
      for (int p = 0; p < 4; ++p) {
        k[2 * p] = ((unsigned long long)__float_as_uint(mind2[p].x) << 32) | nlo[2 * p];
        k[2 * p + 1] =
            ((unsigned long long)__float_as_uint(mind2[p].y) << 32) | nlo[2 * p + 1];
      }
#pragma unroll
      for (int s = 4; s; s >>= 1)
#pragma unroll
        for (int i = 0; i < s; ++i) k[i] = k[i] > k[i + s] ? k[i] : k[i + s];
      unsigned long long key = k[0];
      key = dppmax_u64<0xB1>(key);   // xor 1
      key = dppmax_u64<0x4E>(key);   // xor 2
      key = dppmax_u64<0x141>(key);  // half-mirror (covers 8)
      key = dppmax_u64<0x140>(key);  // mirror (covers 16)
      key = swzmax16_u64(key);       // xor 16 -> 32-lane uniform
      const int buf = it & 1;
      if ((lane & 31) == 0) sm.f.part[buf][(t >> 6) * 2 + (lane >> 5)] = key;
      __syncthreads();
      unsigned long long rk = sm.f.part[buf][lane & 15];
      rk = dppmax_u64<0xB1>(rk);
      rk = dppmax_u64<0x4E>(rk);
      rk = dppmax_u64<0x141>(rk);
      rk = dppmax_u64<0x140>(rk);
      const unsigned idx = ~(unsigned)rk;  // winner (block-uniform)
      cx = sm.f.lx[idx]; cy = sm.f.ly[idx]; cz = sm.f.lz[idx];  // 3 broadcast reads
    }
    __syncthreads();
    float* ob = out_xyz + (size_t)b * NPOINT * 3;
    for (int i = t; i < NPOINT * 3; i += 512) ob[i] = sm.f.scen[i];
  } else {
    // ================= P1 (one row per thread) =================
    {
      const float4* w4 = (const float4*)(W0 + 192);
      float4* s4 = (float4*)sm.sw;
      s4[t] = w4[t]; s4[t + 512] = w4[t + 512];
    }
    __syncthreads();
    const size_t r = (size_t)(blockIdx.x - NB) * 512 + t;
    const float* prow = pts + r * 64;
    float acc[64];
#pragma unroll
    for (int d = 0; d < 64; ++d) acc[d] = 0.0f;
#pragma unroll
    for (int cq = 0; cq < 16; ++cq) {
      const float4 p4 = *(const float4*)(prow + cq * 4);
      const float pv[4] = {p4.x, p4.y, p4.z, p4.w};
#pragma unroll
      for (int u = 0; u < 4; ++u) {
        const int c = cq * 4 + u;
#pragma unroll
        for (int d4 = 0; d4 < 16; ++d4) {
          const float4 w = *(const float4*)(&sm.sw[c * 64 + d4 * 4]);
          acc[d4 * 4 + 0] = fmaf(pv[u], w.x, acc[d4 * 4 + 0]);
          acc[d4 * 4 + 1] = fmaf(pv[u], w.y, acc[d4 * 4 + 1]);
          acc[d4 * 4 + 2] = fmaf(pv[u], w.z, acc[d4 * 4 + 2]);
          acc[d4 * 4 + 3] = fmaf(pv[u], w.w, acc[d4 * 4 + 3]);
        }
      }
    }
    float* o = P1 + r * 64;
#pragma unroll
    for (int d4 = 0; d4 < 16; ++d4)
      *(float4*)(o + d4 * 4) = make_float4(acc[d4 * 4 + 0], acc[d4 * 4 + 1],
                                           acc[d4 * 4 + 2], acc[d4 * 4 + 3]);
  }
}

// ---------------------------------------------------------------------------
// Ball query (proven R6): one wave per query; ballot + prefix popcount;
// uniform early exit at 32 hits.
// ---------------------------------------------------------------------------
__global__ __launch_bounds__(256) void ballq_kernel(const float* __restrict__ xyz,
                                                    const float* __restrict__ new_xyz,
                                                    int* __restrict__ ballidx,
                                                    float* __restrict__ out_idx) {
  __shared__ int sidx[4][NSAMPLE];
  const int wv = threadIdx.x >> 6, lane = threadIdx.x & 63;
  const int q = blockIdx.x * 4 + wv;
  const int b = q >> 10;
  const float* g = xyz + (size_t)b * NPTS * 3;
  const float nx = new_xyz[(size_t)q * 3];
  const float ny = new_xyz[(size_t)q * 3 + 1];
  const float nz = new_xyz[(size_t)q * 3 + 2];
  const float r2 = (float)(0.2 * 0.2);  // double->f32 (NOT 0.2f*0.2f)
  int cnt = 0;
  for (int base = 0; base < NPTS; base += 64) {
    const int j = base + lane;
    const float dx = __fsub_rn(g[3 * j], nx);
    const float dy = __fsub_rn(g[3 * j + 1], ny);
    const float dz = __fsub_rn(g[3 * j + 2], nz);
    const float d2 = __fadd_rn(__fadd_rn(__fmul_rn(dx, dx), __fmul_rn(dy, dy)),
                               __fmul_rn(dz, dz));
    const bool hit = d2 <= r2;
    const unsigned long long m = __ballot(hit);
    const int pos = cnt + __popcll(m & ((1ull << lane) - 1ull));
    if (hit && pos < NSAMPLE) sidx[wv][pos] = j;
    cnt += __popcll(m);
    if (cnt >= NSAMPLE) break;  // wave-uniform
  }
  __syncthreads();
  const int capped = cnt < NSAMPLE ? cnt : NSAMPLE;
  if (lane < NSAMPLE) {
    const int v = sidx[wv][lane < capped ? lane : 0];  // pad with first hit
    ballidx[(size_t)q * NSAMPLE + lane] = v;
    out_idx[(size_t)q * NSAMPLE + lane] = (float)v;
  }
}

// ---------------------------------------------------------------------------
// MLP (exact R6 scalar version, proven 225us): uniform VMEM weight loads
// (L1-broadcast, L2-hot), fmaf accumulation, k-max via __shfl_xor.
// ---------------------------------------------------------------------------
__global__ __launch_bounds__(256) void mlp_kernel(
    const float* __restrict__ xyz, const float* __restrict__ new_xyz,
    const int* __restrict__ ballidx, const float* __restrict__ P1,
    const float* __restrict__ W0, const float* __restrict__ b0,
    const float* __restrict__ W1, const float* __restrict__ b1,
    const float* __restrict__ W2, const float* __restrict__ b2,
    float* __restrict__ out_np) {
  const int t = threadIdx.x;
  const int item = blockIdx.x * 256 + t;
  const int k = item & 31;
  const int q = item >> 5;
  const int b = q >> 10;
  const int idx = ballidx[(size_t)q * 32 + k];
  const float nx = new_xyz[(size_t)q * 3];
  const float ny = new_xyz[(size_t)q * 3 + 1];
  const float nz = new_xyz[(size_t)q * 3 + 2];
  const float* p = xyz + ((size_t)b * NPTS + idx) * 3;
  const float dx = p[0] - nx, dy = p[1] - ny, dz = p[2] - nz;

  float h1[64];
  const float* p1r = P1 + ((size_t)b * NPTS + idx) * 64;
#pragma unroll
  for (int d4 = 0; d4 < 16; ++d4) {
    const float4 pv = *(const float4*)(p1r + d4 * 4);
    const float pe[4] = {pv.x, pv.y, pv.z, pv.w};
#pragma unroll
    for (int u = 0; u < 4; ++u) {
      const int d = d4 * 4 + u;
      const float v = pe[u] + dx * W0[d] + dy * W0[64 + d] + dz * W0[128 + d] + b0[d];
      h1[d] = fmaxf(v, 0.0f);
    }
  }

  float h2[64];
#pragma unroll
  for (int j4 = 0; j4 < 16; ++j4) {
    const float4 bb = *(const float4*)(&b1[j4 * 4]);
    h2[j4 * 4 + 0] = bb.x; h2[j4 * 4 + 1] = bb.y;
    h2[j4 * 4 + 2] = bb.z; h2[j4 * 4 + 3] = bb.w;
  }
#pragma unroll
  for (int c = 0; c < 64; ++c) {
    const float hc = h1[c];
#pragma unroll
    for (int j4 = 0; j4 < 16; ++j4) {
      const float4 w = *(const float4*)(&W1[c * 64 + j4 * 4]);
      h2[j4 * 4 + 0] = fmaf(hc, w.x, h2[j4 * 4 + 0]);
      h2[j4 * 4 + 1] = fmaf(hc, w.y, h2[j4 * 4 + 1]);
      h2[j4 * 4 + 2] = fmaf(hc, w.z, h2[j4 * 4 + 2]);
      h2[j4 * 4 + 3] = fmaf(hc, w.w, h2[j4 * 4 + 3]);
    }
  }
#pragma unroll
  for (int j = 0; j < 64; ++j) h2[j] = fmaxf(h2[j], 0.0f);

  float* outq = out_np + (size_t)q * 128;
  for (int jb = 0; jb < 4; ++jb) {
    float acc[32];
#pragma unroll
    for (int j8 = 0; j8 < 8; ++j8) {
      const float4 bb = *(const float4*)(&b2[jb * 32 + j8 * 4]);
      acc[j8 * 4 + 0] = bb.x; acc[j8 * 4 + 1] = bb.y;
      acc[j8 * 4 + 2] = bb.z; acc[j8 * 4 + 3] = bb.w;
    }
#pragma unroll
    for (int c = 0; c < 64; ++c) {
      const float hc = h2[c];
#pragma unroll
      for (int j8 = 0; j8 < 8; ++j8) {
        const float4 w = *(const float4*)(&W2[c * 128 + jb * 32 + j8 * 4]);
        acc[j8 * 4 + 0] = fmaf(hc, w.x, acc[j8 * 4 + 0]);
        acc[j8 * 4 + 1] = fmaf(hc, w.y, acc[j8 * 4 + 1]);
        acc[j8 * 4 + 2] = fmaf(hc, w.z, acc[j8 * 4 + 2]);
        acc[j8 * 4 + 3] = fmaf(hc, w.w, acc[j8 * 4 + 3]);
      }
    }
#pragma unroll
    for (int j = 0; j < 32; ++j) acc[j] = fmaxf(acc[j], 0.0f);
#pragma unroll
    for (int msk = 16; msk >= 1; msk >>= 1) {
#pragma unroll
      for (int j = 0; j < 32; ++j) acc[j] = fmaxf(acc[j], __shfl_xor(acc[j], msk, 64));
    }
    if (k == 0) {
#pragma unroll
      for (int j8 = 0; j8 < 8; ++j8)
        *(float4*)(outq + jb * 32 + j8 * 4) =
            make_float4(acc[j8 * 4 + 0], acc[j8 * 4 + 1], acc[j8 * 4 + 2], acc[j8 * 4 + 3]);
    }
  }
}

extern "C" void kernel_launch(void* const* d_in, const int* in_sizes, int n_in,
                              void* d_out, int out_size, void* d_ws, size_t ws_size,
                              hipStream_t stream) {
  const float* xyz = (const float*)d_in[0];
  const float* pts = (const float*)d_in[1];
  const float* W0  = (const float*)d_in[2];
  const float* b0  = (const float*)d_in[3];
  const float* W1  = (const float*)d_in[4];
  const float* b1  = (const float*)d_in[5];
  const float* W2  = (const float*)d_in[6];
  const float* b2  = (const float*)d_in[7];

  float* out      = (float*)d_out;
  float* out_xyz  = out;                       // [16,1024,3]
  float* out_np   = out + 16 * 1024 * 3;       // [16,1024,128]
  float* out_idx  = out_np + 16 * 1024 * 128;  // [16,1024,32] as float values

  int*   ballidx = (int*)d_ws;                          // 2 MB
  float* P1      = (float*)((char*)d_ws + (2u << 20));  // 16 MB

  fps_p1_kernel<<<NB + 128, 512, 0, stream>>>(xyz, pts, W0, out_xyz, P1);
  ballq_kernel<<<4096, 256, 0, stream>>>(xyz, out_xyz, ballidx, out_idx);
  mlp_kernel<<<2048, 256, 0, stream>>>(xyz, out_xyz, ballidx, P1,
                                       W0, b0, W1, b1, W2, b2, out_np);
}